// Round 1
// baseline (49.902 us; speedup 1.0000x reference)
//
#include <hip/hip_runtime.h>

#define EPS 1e-5f

// One workgroup per (b, i): computes the full 3-row stripe of the Hessian
// for atom i, accumulating the diagonal 3x3 block on the fly.
__global__ __launch_bounds__(256) void c2s_kernel(
    const float* __restrict__ coords,
    const int*   __restrict__ num_atoms,
    float*       __restrict__ out,
    int N)
{
    const int i   = blockIdx.x;
    const int b   = blockIdx.y;
    const int tid = threadIdx.x;
    const int n3  = 3 * N;

    const float* cb = coords + (size_t)b * n3;
    const int na   = num_atoms[b];
    const bool vi  = (i < na);

    const float cix = cb[3 * i + 0];
    const float ciy = cb[3 * i + 1];
    const float ciz = cb[3 * i + 2];

    float sxx = 0.f, sxy = 0.f, sxz = 0.f, syy = 0.f, syz = 0.f, szz = 0.f;

    float* r0 = out + ((size_t)b * n3 + (size_t)(3 * i)) * n3;
    float* r1 = r0 + n3;
    float* r2 = r1 + n3;

    for (int j0 = 0; j0 < N; j0 += 256) {
        const int j = j0 + tid;
        // pair mask: zero sep outside the valid block (EPS still added after)
        const float m = (vi && (j < na)) ? 1.0f : 0.0f;
        const float dx = (cix - cb[3 * j + 0]) * m;
        const float dy = (ciy - cb[3 * j + 1]) * m;
        const float dz = (ciz - cb[3 * j + 2]) * m;
        const float inv = 1.0f / (dx * dx + dy * dy + dz * dz + EPS);
        const float hxx = dx * dx * inv, hxy = dx * dy * inv, hxz = dx * dz * inv;
        const float hyy = dy * dy * inv, hyz = dy * dz * inv, hzz = dz * dz * inv;
        // diagonal block = -sum_j hess[i][j] = +sum_j sep⊗sep/dist2
        sxx += hxx; sxy += hxy; sxz += hxz;
        syy += hyy; syz += hyz; szz += hzz;
        if (j != i) {
            r0[3 * j + 0] = -hxx; r0[3 * j + 1] = -hxy; r0[3 * j + 2] = -hxz;
            r1[3 * j + 0] = -hxy; r1[3 * j + 1] = -hyy; r1[3 * j + 2] = -hyz;
            r2[3 * j + 0] = -hxz; r2[3 * j + 1] = -hyz; r2[3 * j + 2] = -hzz;
        }
    }

    // block-wide reduction of the 6 unique diagonal-block sums
    #pragma unroll
    for (int off = 32; off > 0; off >>= 1) {
        sxx += __shfl_down(sxx, off);
        sxy += __shfl_down(sxy, off);
        sxz += __shfl_down(sxz, off);
        syy += __shfl_down(syy, off);
        syz += __shfl_down(syz, off);
        szz += __shfl_down(szz, off);
    }
    __shared__ float red[4][6];
    const int wave = tid >> 6;
    const int lane = tid & 63;
    if (lane == 0) {
        red[wave][0] = sxx; red[wave][1] = sxy; red[wave][2] = sxz;
        red[wave][3] = syy; red[wave][4] = syz; red[wave][5] = szz;
    }
    __syncthreads();
    if (tid == 0) {
        const float dxx = red[0][0] + red[1][0] + red[2][0] + red[3][0];
        const float dxy = red[0][1] + red[1][1] + red[2][1] + red[3][1];
        const float dxz = red[0][2] + red[1][2] + red[2][2] + red[3][2];
        const float dyy = red[0][3] + red[1][3] + red[2][3] + red[3][3];
        const float dyz = red[0][4] + red[1][4] + red[2][4] + red[3][4];
        const float dzz = red[0][5] + red[1][5] + red[2][5] + red[3][5];
        r0[3 * i + 0] = dxx; r0[3 * i + 1] = dxy; r0[3 * i + 2] = dxz;
        r1[3 * i + 0] = dxy; r1[3 * i + 1] = dyy; r1[3 * i + 2] = dyz;
        r2[3 * i + 0] = dxz; r2[3 * i + 1] = dyz; r2[3 * i + 2] = dzz;
    }
}

extern "C" void kernel_launch(void* const* d_in, const int* in_sizes, int n_in,
                              void* d_out, int out_size, void* d_ws, size_t ws_size,
                              hipStream_t stream) {
    const float* coords    = (const float*)d_in[0];
    const int*   num_atoms = (const int*)d_in[1];
    float*       out       = (float*)d_out;

    const int B = in_sizes[1];             // 8
    const int N = in_sizes[0] / (3 * B);   // 1024

    dim3 grid(N, B);
    c2s_kernel<<<grid, 256, 0, stream>>>(coords, num_atoms, out, N);
}